// Round 21
// baseline (338.170 us; speedup 1.0000x reference)
//
#include <hip/hip_runtime.h>
#include <hip/hip_bf16.h>

#define NR 12288
#define DIMS 256
#define RB 512              // row bytes = DIMS * 2 (bf16)
#define NT 192              // 64-row tiles
#define NCH 8               // A-side buckets per row (= s index)
#define NCH0 4              // threshold-pass sub-chunks
#define W0 768              // threshold sample width: cols [0, 768)
#define CW0 (W0 / NCH0)     // 192
#define TOPP 9

typedef __attribute__((ext_vector_type(8))) short short8v;
typedef __attribute__((ext_vector_type(4))) float f32x4;

__device__ __forceinline__ unsigned short f2bf(float f) {
    unsigned int u = __float_as_uint(f);
    u += 0x7fffu + ((u >> 16) & 1u);
    return (unsigned short)(u >> 16);
}

// Sortable key: top 18 bits = monotone-mapped float, low 14 = col (unique).
__device__ __forceinline__ unsigned packkey(float v, int col) {
    unsigned u = __float_as_uint(v);
    u ^= (unsigned)((int)u >> 31) | 0x80000000u;
    return (u & 0xFFFFC000u) | (unsigned)col;
}

// Keep 9 largest unique keys; sentinels lane-unique before cross-lane merges.
__device__ __forceinline__ void top9u(unsigned (&a)[9], unsigned& mn, unsigned key) {
    if (key > mn) {
#pragma unroll
        for (int k = 0; k < 9; ++k) a[k] = (a[k] == mn) ? key : a[k];
        unsigned m = a[0];
#pragma unroll
        for (int k = 1; k < 9; ++k) m = min(m, a[k]);
        mn = m;
    }
}

// ---------- 1) row-normalize fp32 -> bf16, one row per wave ----------
__global__ void k_norm(const float* __restrict__ x, unsigned short* __restrict__ emb) {
    const int wave = threadIdx.x >> 6, lane = threadIdx.x & 63;
    const int row = blockIdx.x * 4 + wave;
    const float4 v = *(const float4*)(x + (size_t)row * DIMS + lane * 4);
    float ss = v.x * v.x + v.y * v.y + v.z * v.z + v.w * v.w;
#pragma unroll
    for (int off = 32; off > 0; off >>= 1) ss += __shfl_xor(ss, off);
    const float inv = 1.0f / fmaxf(sqrtf(ss), 1e-12f);
    ushort4 o;
    o.x = f2bf(v.x * inv); o.y = f2bf(v.y * inv);
    o.z = f2bf(v.z * inv); o.w = f2bf(v.w * inv);
    *(ushort4*)(emb + (size_t)row * DIMS + lane * 4) = o;
}

// Half-K tile in LDS: 64 cols x 128 K = 16 KB; byte b (col=b>>8) stored at
// b ^ ((col&7)<<4) -> staged writes and fragment reads at the 8-round floor.
__device__ __forceinline__ const short8v* frag_ptr(const char* buf, int col, int kkl, int lg) {
    const int b = (col << 8) + (kkl << 6) + (lg << 4);
    return (const short8v*)(buf + (b ^ ((col & 7) << 4)));
}

#define STAGE_LOAD_J(JT, HOFF)                                                 \
    {                                                                          \
        const char* p_ = embB + (size_t)((JT) * 64 + colA) * RB + (HOFF) + win; \
        g0 = *(const uint4*)(p_);                                              \
        g1 = *(const uint4*)(p_ + 16 * RB);                                    \
        g2 = *(const uint4*)(p_ + 32 * RB);                                    \
        g3 = *(const uint4*)(p_ + 48 * RB);                                    \
    }

#define STAGE_WRITE(SB)                                                        \
    {                                                                          \
        char* d_ = (SB) + colA * 256 + (win ^ swzA);                           \
        *(uint4*)(d_ + 0)     = g0;                                            \
        *(uint4*)(d_ + 4096)  = g1;                                            \
        *(uint4*)(d_ + 8192)  = g2;                                            \
        *(uint4*)(d_ + 12288) = g3;                                            \
    }

#define GEMM_EVEN(SB, KO)                                                      \
    _Pragma("unroll")                                                          \
    for (int kkl = 0; kkl < 4; ++kkl) {                                        \
        short8v b0 = *frag_ptr(SB,      l15, kkl, lg);                         \
        short8v b1 = *frag_ptr(SB, 16 + l15, kkl, lg);                         \
        short8v b2 = *frag_ptr(SB, 32 + l15, kkl, lg);                         \
        short8v b3 = *frag_ptr(SB, 48 + l15, kkl, lg);                         \
        acc0 = __builtin_amdgcn_mfma_f32_16x16x32_bf16(aF[(KO)+kkl], b0, acc0, 0, 0, 0); \
        acc1 = __builtin_amdgcn_mfma_f32_16x16x32_bf16(aF[(KO)+kkl], b1, acc1, 0, 0, 0); \
        acc2 = __builtin_amdgcn_mfma_f32_16x16x32_bf16(aF[(KO)+kkl], b2, acc2, 0, 0, 0); \
        acc3 = __builtin_amdgcn_mfma_f32_16x16x32_bf16(aF[(KO)+kkl], b3, acc3, 0, 0, 0); \
    }

// ---------- 2) k_sub9: exact per-row top-9 keys over cols [0, W0) ----------
__global__ __launch_bounds__(256, 2) void k_sub9(const unsigned short* __restrict__ emb,
                                                 unsigned* __restrict__ s9p) {
    const int bid = blockIdx.x;
    const int chunk = bid & 3, rb = bid >> 2;
    const int w = threadIdx.x >> 6, lane = threadIdx.x & 63;
    const int l15 = lane & 15, lg = lane >> 4;
    const int R0 = rb * 64 + w * 16;
    const int Cb = chunk * CW0;
    const char* embB = (const char*)emb;
    const int colA = threadIdx.x >> 4;
    const int win = (threadIdx.x & 15) * 16;
    const int swzA = (colA & 7) << 4;

    __shared__ __align__(1024) char sb0[16384];
    __shared__ __align__(1024) char sb1[16384];

    short8v aF[8];
    const unsigned short* ab = emb + (size_t)(R0 + l15) * DIMS + lg * 8;
#pragma unroll
    for (int kk = 0; kk < 8; ++kk) aF[kk] = *(const short8v*)(ab + kk * 32);

    unsigned t9[4][9]; unsigned kmin[4];
#pragma unroll
    for (int r = 0; r < 4; ++r) {
        kmin[r] = (unsigned)(lane * 16);
#pragma unroll
        for (int k = 0; k < 9; ++k) t9[r][k] = (unsigned)(lane * 16 + k);   // lane-unique
    }

    uint4 g0, g1, g2, g3;
    STAGE_LOAD_J(0, Cb * RB)   // JT=0 with byte offset trick unused; use explicit below
    // (explicit form to keep addressing identical to r20:)
    {
        const char* p_ = embB + (size_t)(Cb + colA) * RB + win;
        g0 = *(const uint4*)(p_);
        g1 = *(const uint4*)(p_ + 16 * RB);
        g2 = *(const uint4*)(p_ + 32 * RB);
        g3 = *(const uint4*)(p_ + 48 * RB);
    }
    STAGE_WRITE(sb0)
    __syncthreads();

    f32x4 acc0, acc1, acc2, acc3;
    const int NCT = CW0 / 64;      // 3 col-tiles, 6 units
    for (int u = 0; u < 2 * NCT; ++u) {
        const int ct = u >> 1;
        const int ctN = (u + 1) >> 1, hN = (u + 1) & 1;
        const bool more = (u + 1 < 2 * NCT);
        if (more) {
            const char* p_ = embB + (size_t)(Cb + ctN * 64 + colA) * RB + hN * 256 + win;
            g0 = *(const uint4*)(p_);
            g1 = *(const uint4*)(p_ + 16 * RB);
            g2 = *(const uint4*)(p_ + 32 * RB);
            g3 = *(const uint4*)(p_ + 48 * RB);
        }
        if ((u & 1) == 0) {
            acc0 = {0.f,0.f,0.f,0.f}; acc1 = {0.f,0.f,0.f,0.f};
            acc2 = {0.f,0.f,0.f,0.f}; acc3 = {0.f,0.f,0.f,0.f};
            GEMM_EVEN(sb0, 0)
        } else {
            GEMM_EVEN(sb1, 4)
            const int c0 = Cb + ct * 64 + l15;
#pragma unroll
            for (int r = 0; r < 4; ++r) {
                top9u(t9[r], kmin[r], packkey(acc0[r], c0));
                top9u(t9[r], kmin[r], packkey(acc1[r], c0 + 16));
                top9u(t9[r], kmin[r], packkey(acc2[r], c0 + 32));
                top9u(t9[r], kmin[r], packkey(acc3[r], c0 + 48));
            }
        }
        if (more) {
            if (hN) STAGE_WRITE(sb1) else STAGE_WRITE(sb0)
        }
        __syncthreads();
    }

    // exact merge across the 16 lanes sharing each row (snapshot-then-insert)
#pragma unroll
    for (int off = 1; off < 16; off <<= 1) {
#pragma unroll
        for (int r = 0; r < 4; ++r) {
            unsigned o[9];
#pragma unroll
            for (int k = 0; k < 9; ++k) o[k] = (unsigned)__shfl_xor((int)t9[r][k], off);
#pragma unroll
            for (int k = 0; k < 9; ++k) top9u(t9[r], kmin[r], o[k]);
        }
    }
    if (l15 == 0) {
#pragma unroll
        for (int r = 0; r < 4; ++r) {
            unsigned* dst = s9p + ((size_t)(R0 + lg * 4 + r) * NCH0 + chunk) * TOPP;
#pragma unroll
            for (int k = 0; k < 9; ++k) dst[k] = t9[r][k];
        }
    }
}

// ---------- 3) merge sub-chunk top-9s -> per-row float filter threshold ----
__global__ void k_thrm(const unsigned* __restrict__ s9p, float* __restrict__ thrF) {
    const int row = blockIdx.x * 256 + threadIdx.x;
    unsigned a[9]; unsigned mn = 0;
#pragma unroll
    for (int k = 0; k < 9; ++k) a[k] = (unsigned)k;   // serial: distinct ok
    const unsigned* src = s9p + (size_t)row * (NCH0 * TOPP);
    for (int c = 0; c < NCH0 * TOPP; ++c) top9u(a, mn, src[c]);
    // float with key-floor == mn's quantum: (v >= tF) <=> key18(v) >= mn&~0x3FFF
    const unsigned T = mn & 0xFFFFC000u;
    thrF[row] = (T & 0x80000000u) ? __uint_as_float(T ^ 0x80000000u)
                                  : __uint_as_float(~T);
}

// ---------- 4) k_main: SYMMETRIC half-GEMM with r20's proven mechanism ------
// Block (I,s): rows of tile I vs J in {I+s, I+s+8,...} (upper triangle).
// Each v=sim[i,j] tested twice: A-side (>=thrF[i] -> (v,j) into row i's
// (row,s) bucket, LDS counter) and B-side (>=thrF[j] -> (v,i) into row j's
// global bucket, global atomic -- rare, scattered). Diag tile A-side only.
// MFMA dot is bitwise commutative (r11 verified on HW) and thresholds have
// quantum slack, so orientation is harmless. o_i==8 by construction in k_sel
// -> any bucket-drop pattern is output-invariant.
__global__ __launch_bounds__(256, 2) void k_main(const unsigned short* __restrict__ emb,
                                                 const float* __restrict__ thrF,
                                                 unsigned* __restrict__ bufg,
                                                 unsigned* __restrict__ cntg,
                                                 unsigned capc,
                                                 unsigned* __restrict__ bufB,
                                                 unsigned* __restrict__ cntB,
                                                 unsigned capB) {
    const int I = blockIdx.x >> 3, s = blockIdx.x & 7;
    const int first = I + s;
    if (first >= NT) {        // no J-tiles: zero our cntg slots and exit
        if (threadIdx.x < 64)
            cntg[(size_t)(I * 64 + threadIdx.x) * NCH + s] = 0;
        return;
    }
    const int M = (NT - 1 - first) / 8 + 1;
    const int w = threadIdx.x >> 6, lane = threadIdx.x & 63;
    const int l15 = lane & 15, lg = lane >> 4;
    const int R0 = I * 64 + w * 16;
    const char* embB = (const char*)emb;
    const int colA = threadIdx.x >> 4;
    const int win = (threadIdx.x & 15) * 16;
    const int swzA = (colA & 7) << 4;

    __shared__ __align__(1024) char sb0[16384];
    __shared__ __align__(1024) char sb1[16384];
    __shared__ unsigned lcnt[64];
    if (threadIdx.x < 64) lcnt[threadIdx.x] = 0;

    short8v aF[8];
    const unsigned short* ab = emb + (size_t)(R0 + l15) * DIMS + lg * 8;
#pragma unroll
    for (int kk = 0; kk < 8; ++kk) aF[kk] = *(const short8v*)(ab + kk * 32);

    float tvf[4];
#pragma unroll
    for (int r = 0; r < 4; ++r) tvf[r] = thrF[R0 + lg * 4 + r];

    uint4 g0, g1, g2, g3;
    STAGE_LOAD_J(first, 0)
    STAGE_WRITE(sb0)
    __syncthreads();

// dual lean append: A-side via LDS counter, B-side via global counter
#define APPEND_SYM(ACC, XOFF)                                                  \
    _Pragma("unroll")                                                          \
    for (int r = 0; r < 4; ++r) {                                              \
        const float v_ = ACC[r];                                               \
        if (v_ >= tvf[r]) {                                                    \
            const int rloc = w * 16 + lg * 4 + r;                              \
            const unsigned idx = atomicAdd(&lcnt[rloc], 1u);                   \
            if (idx < capc)                                                    \
                bufg[((size_t)(R0 + lg * 4 + r) * NCH + s) * capc + idx] =     \
                    packkey(v_, Jb + (XOFF) + l15);                            \
        }                                                                      \
        if (ndiag) {                                                           \
            const float tvJ_ = __shfl(tvJl, (XOFF) + l15);                     \
            if (v_ >= tvJ_) {                                                  \
                const int jc = Jb + (XOFF) + l15;                              \
                const unsigned idx = atomicAdd(&cntB[jc], 1u);                 \
                if (idx < capB)                                                \
                    bufB[(size_t)jc * capB + idx] = packkey(v_, R0 + lg * 4 + r); \
            }                                                                  \
        }                                                                      \
    }

    f32x4 acc0, acc1, acc2, acc3;
    const int units = 2 * M;
    for (int u = 0; u < units; ++u) {
        const int Jt = first + 8 * (u >> 1);
        const int hN = (u + 1) & 1;
        const bool more = (u + 1 < units);
        if (more) STAGE_LOAD_J(first + 8 * ((u + 1) >> 1), hN * 256)
        float tvJl = 0.0f;
        if (u & 1) tvJl = thrF[Jt * 64 + lane];
        if ((u & 1) == 0) {
            acc0 = {0.f,0.f,0.f,0.f}; acc1 = {0.f,0.f,0.f,0.f};
            acc2 = {0.f,0.f,0.f,0.f}; acc3 = {0.f,0.f,0.f,0.f};
            GEMM_EVEN(sb0, 0)
        } else {
            GEMM_EVEN(sb1, 4)
            const int Jb = Jt * 64;
            const bool ndiag = (Jt != I);
            APPEND_SYM(acc0, 0)
            APPEND_SYM(acc1, 16)
            APPEND_SYM(acc2, 32)
            APPEND_SYM(acc3, 48)
        }
        if (more) {
            if (hN) STAGE_WRITE(sb1) else STAGE_WRITE(sb0)
        }
        __syncthreads();
    }

    if (threadIdx.x < 64)
        cntg[(size_t)(I * 64 + threadIdx.x) * NCH + s] = lcnt[threadIdx.x];
#undef APPEND_SYM
}

// ---------- 5) k_sel: wave-parallel select over A-buckets + B-bucket --------
// 16 lanes/row, strided reads, butterfly merge (lane-unique sentinels);
// synthetic diag key by lane 0 only -> o_i == 8 for any bucket-drop pattern.
__global__ void k_sel(const unsigned* __restrict__ bufg, const unsigned* __restrict__ cntg,
                      unsigned capc,
                      const unsigned* __restrict__ bufB, const unsigned* __restrict__ cntB,
                      unsigned capB,
                      unsigned* __restrict__ dd, unsigned* __restrict__ gg) {
    const int w = threadIdx.x >> 6, lane = threadIdx.x & 63;
    const int l15 = lane & 15, lg = lane >> 4;
    const int row = blockIdx.x * 16 + w * 4 + lg;

    unsigned a[9]; unsigned mn = (unsigned)(l15 * 16);
#pragma unroll
    for (int k = 0; k < 9; ++k) a[k] = (unsigned)(l15 * 16 + k);   // lane-unique
    if (l15 == 0) top9u(a, mn, 0xFFFFC000u | (unsigned)row);       // synthetic diag
#pragma unroll
    for (int c = 0; c < NCH; ++c) {
        const unsigned n = min(cntg[(size_t)row * NCH + c], capc);
        const unsigned* b = bufg + ((size_t)row * NCH + c) * capc;
        for (unsigned t = l15; t < n; t += 16) {
            const unsigned key = b[t];
            if ((key & 16383u) != (unsigned)row) top9u(a, mn, key);
        }
    }
    {
        const unsigned n = min(cntB[row], capB);
        const unsigned* b = bufB + (size_t)row * capB;
        for (unsigned t = l15; t < n; t += 16) {
            const unsigned key = b[t];
            if ((key & 16383u) != (unsigned)row) top9u(a, mn, key);
        }
    }
#pragma unroll
    for (int off = 1; off < 16; off <<= 1) {
        unsigned o[9];
#pragma unroll
        for (int k = 0; k < 9; ++k) o[k] = (unsigned)__shfl_xor((int)a[k], off);
#pragma unroll
        for (int k = 0; k < 9; ++k) top9u(a, mn, o[k]);
    }
    const unsigned thr = mn;   // exact 9th of {synth diag} u survivors
    unsigned o = 0;
#pragma unroll
    for (int c = 0; c < NCH; ++c) {
        const unsigned n = min(cntg[(size_t)row * NCH + c], capc);
        const unsigned* b = bufg + ((size_t)row * NCH + c) * capc;
        for (unsigned t = l15; t < n; t += 16) {
            const unsigned key = b[t];
            const int col = (int)(key & 16383u);
            if (key >= thr && col != row) { ++o; atomicAdd(&gg[col], 1u); }
        }
    }
    {
        const unsigned n = min(cntB[row], capB);
        const unsigned* b = bufB + (size_t)row * capB;
        for (unsigned t = l15; t < n; t += 16) {
            const unsigned key = b[t];
            const int col = (int)(key & 16383u);
            if (key >= thr && col != row) { ++o; atomicAdd(&gg[col], 1u); }
        }
    }
#pragma unroll
    for (int off = 1; off < 16; off <<= 1) o += (unsigned)__shfl_xor((int)o, off);
    if (l15 == 0) dd[row] = o;
}

// ---------- 6) wsum = sum_i o*d + g*d - 2o, d = max(o,1) ----------
__global__ void k_wsum(const unsigned* __restrict__ dd, const unsigned* __restrict__ gg,
                       unsigned long long* __restrict__ wsum) {
    const int i = blockIdx.x * 256 + threadIdx.x;
    const unsigned long long o = dd[i];
    const unsigned long long g = gg[i];
    const unsigned long long d = o ? o : 1ull;
    unsigned long long acc = o * d + g * d - 2ull * o;
#pragma unroll
    for (int off = 32; off > 0; off >>= 1) acc += __shfl_xor(acc, off);
    if ((threadIdx.x & 63) == 0 && acc) atomicAdd(wsum, acc);
}

// ---------- 7) finalize ----------
__global__ void k_fin(const unsigned long long* __restrict__ wsum, float* __restrict__ out) {
    out[0] = (float)((double)*wsum * (0.01 / ((double)NR * (double)NR)));
}

extern "C" void kernel_launch(void* const* d_in, const int* in_sizes, int n_in,
                              void* d_out, int out_size, void* d_ws, size_t ws_size,
                              hipStream_t stream) {
    const float* x = (const float*)d_in[0];
    float* out = (float*)d_out;
    char* ws = (char*)d_ws;

    size_t off = 0;
    unsigned short* emb = (unsigned short*)(ws + off); off += (size_t)NR * DIMS * 2;        // 6.29 MB
    unsigned* s9p = (unsigned*)(ws + off);            off += (size_t)NR * NCH0 * TOPP * 4;  // 1.77 MB
    float* thrF = (float*)(ws + off);                 off += (size_t)NR * 4;
    unsigned* cntg = (unsigned*)(ws + off);           off += (size_t)NR * NCH * 4;          // 393 KB
    unsigned* cntB = (unsigned*)(ws + off);           off += (size_t)NR * 4;
    unsigned* dd = (unsigned*)(ws + off);             off += (size_t)NR * 4;
    unsigned* gg = (unsigned*)(ws + off);             off += (size_t)NR * 4;
    unsigned long long* wsum = (unsigned long long*)(ws + off); off += 64;
    unsigned* bufg = (unsigned*)(ws + off);           off += (size_t)NR * NCH * 32 * 4;     // 12.6 MB (capc=32)
    unsigned* bufB = (unsigned*)(ws + off);
    const unsigned capc = 32u;
    // B bucket capacity from remaining workspace (E ~72-144 for high tiles)
    size_t remB = (ws_size > off) ? (ws_size - off) / ((size_t)NR * 4) : 64;
    unsigned capB = (unsigned)(remB < 64 ? 64 : (remB > 256 ? 256 : remB));

    hipMemsetAsync(cntB, 0, (size_t)NR * 4, stream);
    hipMemsetAsync(gg, 0, (size_t)NR * 4, stream);
    hipMemsetAsync(wsum, 0, 8, stream);

    k_norm<<<NR / 4, 256, 0, stream>>>(x, emb);
    k_sub9<<<(NR / 64) * NCH0, 256, 0, stream>>>(emb, s9p);
    k_thrm<<<NR / 256, 256, 0, stream>>>(s9p, thrF);
    k_main<<<NT * 8, 256, 0, stream>>>(emb, thrF, bufg, cntg, capc, bufB, cntB, capB);
    k_sel<<<NR / 16, 256, 0, stream>>>(bufg, cntg, capc, bufB, cntB, capB, dd, gg);
    k_wsum<<<NR / 256, 256, 0, stream>>>(dd, gg, wsum);
    k_fin<<<1, 1, 0, stream>>>(wsum, out);
}

// Round 22
// 224.475 us; speedup vs baseline: 1.5065x; 1.5065x over previous
//
#include <hip/hip_runtime.h>
#include <hip/hip_bf16.h>

#define NR 12288
#define DIMS 256
#define RB 512              // row bytes = DIMS * 2 (bf16)
#define NCH 8               // main-pass col chunks (1536 cols, chunk == XCD)
#define CWM 1536
#define NCH0 4              // threshold-pass sub-chunks
#define W0 768              // threshold sample width: cols [0, 768)
#define CW0 (W0 / NCH0)     // 192
#define TOPP 9

typedef __attribute__((ext_vector_type(8))) short short8v;
typedef __attribute__((ext_vector_type(4))) float f32x4;

__device__ __forceinline__ unsigned short f2bf(float f) {
    unsigned int u = __float_as_uint(f);
    u += 0x7fffu + ((u >> 16) & 1u);
    return (unsigned short)(u >> 16);
}

// Sortable key: top 18 bits = monotone-mapped float, low 14 = col (unique).
__device__ __forceinline__ unsigned packkey(float v, int col) {
    unsigned u = __float_as_uint(v);
    u ^= (unsigned)((int)u >> 31) | 0x80000000u;
    return (u & 0xFFFFC000u) | (unsigned)col;
}

// Keep 9 largest unique keys; sentinels lane-unique before cross-lane merges.
__device__ __forceinline__ void top9u(unsigned (&a)[9], unsigned& mn, unsigned key) {
    if (key > mn) {
#pragma unroll
        for (int k = 0; k < 9; ++k) a[k] = (a[k] == mn) ? key : a[k];
        unsigned m = a[0];
#pragma unroll
        for (int k = 1; k < 9; ++k) m = min(m, a[k]);
        mn = m;
    }
}

// ---------- 1) row-normalize fp32 -> bf16, one row per wave ----------
__global__ void k_norm(const float* __restrict__ x, unsigned short* __restrict__ emb) {
    const int wave = threadIdx.x >> 6, lane = threadIdx.x & 63;
    const int row = blockIdx.x * 4 + wave;
    const float4 v = *(const float4*)(x + (size_t)row * DIMS + lane * 4);
    float ss = v.x * v.x + v.y * v.y + v.z * v.z + v.w * v.w;
#pragma unroll
    for (int off = 32; off > 0; off >>= 1) ss += __shfl_xor(ss, off);
    const float inv = 1.0f / fmaxf(sqrtf(ss), 1e-12f);
    ushort4 o;
    o.x = f2bf(v.x * inv); o.y = f2bf(v.y * inv);
    o.z = f2bf(v.z * inv); o.w = f2bf(v.w * inv);
    *(ushort4*)(emb + (size_t)row * DIMS + lane * 4) = o;
}

// Half-K tile in LDS: 64 cols x 128 K = 16 KB; byte b (col=b>>8) stored at
// b ^ ((col&7)<<4) -> staged writes and fragment reads at the 8-round floor.
__device__ __forceinline__ const short8v* frag_ptr(const char* buf, int col, int kkl, int lg) {
    const int b = (col << 8) + (kkl << 6) + (lg << 4);
    return (const short8v*)(buf + (b ^ ((col & 7) << 4)));
}

#define STAGE_LOAD(CT, HOFF)                                                   \
    {                                                                          \
        const char* p_ = embB + (size_t)(Cb + (CT) * 64 + colA) * RB + (HOFF) + win; \
        g0 = *(const uint4*)(p_);                                              \
        g1 = *(const uint4*)(p_ + 16 * RB);                                    \
        g2 = *(const uint4*)(p_ + 32 * RB);                                    \
        g3 = *(const uint4*)(p_ + 48 * RB);                                    \
    }

#define STAGE_WRITE(SB)                                                        \
    {                                                                          \
        char* d_ = (SB) + colA * 256 + (win ^ swzA);                           \
        *(uint4*)(d_ + 0)     = g0;                                            \
        *(uint4*)(d_ + 4096)  = g1;                                            \
        *(uint4*)(d_ + 8192)  = g2;                                            \
        *(uint4*)(d_ + 12288) = g3;                                            \
    }

#define GEMM_EVEN(SB, KO)                                                      \
    _Pragma("unroll")                                                          \
    for (int kkl = 0; kkl < 4; ++kkl) {                                        \
        short8v b0 = *frag_ptr(SB,      l15, kkl, lg);                         \
        short8v b1 = *frag_ptr(SB, 16 + l15, kkl, lg);                         \
        short8v b2 = *frag_ptr(SB, 32 + l15, kkl, lg);                         \
        short8v b3 = *frag_ptr(SB, 48 + l15, kkl, lg);                         \
        acc0 = __builtin_amdgcn_mfma_f32_16x16x32_bf16(aF[(KO)+kkl], b0, acc0, 0, 0, 0); \
        acc1 = __builtin_amdgcn_mfma_f32_16x16x32_bf16(aF[(KO)+kkl], b1, acc1, 0, 0, 0); \
        acc2 = __builtin_amdgcn_mfma_f32_16x16x32_bf16(aF[(KO)+kkl], b2, acc2, 0, 0, 0); \
        acc3 = __builtin_amdgcn_mfma_f32_16x16x32_bf16(aF[(KO)+kkl], b3, acc3, 0, 0, 0); \
    }

// ---------- 2) k_sub9: exact per-row top-9 keys over cols [0, W0) ----------
// (256,2): the proven register config (r16 lesson: (256,4) sinks aF).
__global__ __launch_bounds__(256, 2) void k_sub9(const unsigned short* __restrict__ emb,
                                                 unsigned* __restrict__ s9p) {
    const int bid = blockIdx.x;
    const int chunk = bid & 3, rb = bid >> 2;
    const int w = threadIdx.x >> 6, lane = threadIdx.x & 63;
    const int l15 = lane & 15, lg = lane >> 4;
    const int R0 = rb * 64 + w * 16;
    const int Cb = chunk * CW0;
    const char* embB = (const char*)emb;
    const int colA = threadIdx.x >> 4;
    const int win = (threadIdx.x & 15) * 16;
    const int swzA = (colA & 7) << 4;

    __shared__ __align__(1024) char sb0[16384];
    __shared__ __align__(1024) char sb1[16384];

    short8v aF[8];
    const unsigned short* ab = emb + (size_t)(R0 + l15) * DIMS + lg * 8;
#pragma unroll
    for (int kk = 0; kk < 8; ++kk) aF[kk] = *(const short8v*)(ab + kk * 32);

    unsigned t9[4][9]; unsigned kmin[4];
#pragma unroll
    for (int r = 0; r < 4; ++r) {
        kmin[r] = (unsigned)(lane * 16);
#pragma unroll
        for (int k = 0; k < 9; ++k) t9[r][k] = (unsigned)(lane * 16 + k);   // lane-unique
    }

    uint4 g0, g1, g2, g3;
    STAGE_LOAD(0, 0)
    STAGE_WRITE(sb0)
    __syncthreads();

    f32x4 acc0, acc1, acc2, acc3;
    const int NCT = CW0 / 64;      // 3 col-tiles, 6 units
    for (int u = 0; u < 2 * NCT; ++u) {
        const int ct = u >> 1;
        const int ctN = (u + 1) >> 1, hN = (u + 1) & 1;
        const bool more = (u + 1 < 2 * NCT);
        if (more) STAGE_LOAD(ctN, hN * 256)
        if ((u & 1) == 0) {
            acc0 = {0.f,0.f,0.f,0.f}; acc1 = {0.f,0.f,0.f,0.f};
            acc2 = {0.f,0.f,0.f,0.f}; acc3 = {0.f,0.f,0.f,0.f};
            GEMM_EVEN(sb0, 0)
        } else {
            GEMM_EVEN(sb1, 4)
            const int c0 = Cb + ct * 64 + l15;
#pragma unroll
            for (int r = 0; r < 4; ++r) {
                top9u(t9[r], kmin[r], packkey(acc0[r], c0));
                top9u(t9[r], kmin[r], packkey(acc1[r], c0 + 16));
                top9u(t9[r], kmin[r], packkey(acc2[r], c0 + 32));
                top9u(t9[r], kmin[r], packkey(acc3[r], c0 + 48));
            }
        }
        if (more) {
            if (hN) STAGE_WRITE(sb1) else STAGE_WRITE(sb0)
        }
        __syncthreads();
    }

    // exact merge across the 16 lanes sharing each row (snapshot-then-insert)
#pragma unroll
    for (int off = 1; off < 16; off <<= 1) {
#pragma unroll
        for (int r = 0; r < 4; ++r) {
            unsigned o[9];
#pragma unroll
            for (int k = 0; k < 9; ++k) o[k] = (unsigned)__shfl_xor((int)t9[r][k], off);
#pragma unroll
            for (int k = 0; k < 9; ++k) top9u(t9[r], kmin[r], o[k]);
        }
    }
    if (l15 == 0) {
#pragma unroll
        for (int r = 0; r < 4; ++r) {
            unsigned* dst = s9p + ((size_t)(R0 + lg * 4 + r) * NCH0 + chunk) * TOPP;
#pragma unroll
            for (int k = 0; k < 9; ++k) dst[k] = t9[r][k];
        }
    }
}

// ---------- 3) merge sub-chunk top-9s -> per-row float filter threshold ----
__global__ void k_thrm(const unsigned* __restrict__ s9p, float* __restrict__ thrF) {
    const int row = blockIdx.x * 256 + threadIdx.x;
    unsigned a[9]; unsigned mn = 0;
#pragma unroll
    for (int k = 0; k < 9; ++k) a[k] = (unsigned)k;   // serial: distinct ok
    const unsigned* src = s9p + (size_t)row * (NCH0 * TOPP);
    for (int c = 0; c < NCH0 * TOPP; ++c) top9u(a, mn, src[c]);
    // float with key-floor == mn's quantum: (v >= tF) <=> key18(v) >= mn&~0x3FFF
    const unsigned T = mn & 0xFFFFC000u;
    thrF[row] = (T & 0x80000000u) ? __uint_as_float(T ^ 0x80000000u)
                                  : __uint_as_float(~T);
}

// ---------- 4) k_main: r6 GEMM body, (256,2), LEAN per-lane append ----------
// Proven best (r20: 153us, VGPR 72, FETCH 26MB). Full-matrix chunked walk;
// per-lane predicated append (~3/64 lanes active per site); k_sel is
// order-independent and o_i==8 by construction. Symmetric half-GEMM retired
// (r11/r21: barrier-bound units cost 2.4-3.4x more than the saved FLOPs).
__global__ __launch_bounds__(256, 2) void k_main(const unsigned short* __restrict__ emb,
                                                 const float* __restrict__ thrF,
                                                 unsigned* __restrict__ bufg,
                                                 unsigned* __restrict__ cntg,
                                                 unsigned capc) {
    const int bid = blockIdx.x;
    const int chunk = bid & 7, rb = bid >> 3;      // chunk == XCD id
    const int w = threadIdx.x >> 6, lane = threadIdx.x & 63;
    const int l15 = lane & 15, lg = lane >> 4;
    const int R0 = rb * 64 + w * 16;
    const int Cb = chunk * CWM;
    const char* embB = (const char*)emb;
    const int colA = threadIdx.x >> 4;
    const int win = (threadIdx.x & 15) * 16;
    const int swzA = (colA & 7) << 4;

    __shared__ __align__(1024) char sb0[16384];
    __shared__ __align__(1024) char sb1[16384];
    __shared__ unsigned lcnt[64];
    if (threadIdx.x < 64) lcnt[threadIdx.x] = 0;

    short8v aF[8];
    const unsigned short* ab = emb + (size_t)(R0 + l15) * DIMS + lg * 8;
#pragma unroll
    for (int kk = 0; kk < 8; ++kk) aF[kk] = *(const short8v*)(ab + kk * 32);

    float tvf[4];
#pragma unroll
    for (int r = 0; r < 4; ++r) tvf[r] = thrF[R0 + lg * 4 + r];

    uint4 g0, g1, g2, g3;
    STAGE_LOAD(0, 0)
    STAGE_WRITE(sb0)
    __syncthreads();

// lean append: surviving lanes only (rare) do their own LDS-atomic + store
#define APPEND_SITE(ACC, XOFF)                                                 \
    _Pragma("unroll")                                                          \
    for (int r = 0; r < 4; ++r) {                                              \
        if (ACC[r] >= tvf[r]) {                                                \
            const int rloc = w * 16 + lg * 4 + r;                              \
            const unsigned idx = atomicAdd(&lcnt[rloc], 1u);                   \
            if (idx < capc)                                                    \
                bufg[((size_t)(R0 + lg * 4 + r) * NCH + chunk) * capc + idx] = \
                    packkey(ACC[r], c0 + (XOFF));                              \
        }                                                                      \
    }

    f32x4 acc0, acc1, acc2, acc3;
    const int NCT = CWM / 64;      // 24 col-tiles, 48 units
    for (int u = 0; u < 2 * NCT; ++u) {
        const int ct = u >> 1;
        const int ctN = (u + 1) >> 1, hN = (u + 1) & 1;
        const bool more = (u + 1 < 2 * NCT);
        if (more) STAGE_LOAD(ctN, hN * 256)
        if ((u & 1) == 0) {
            acc0 = {0.f,0.f,0.f,0.f}; acc1 = {0.f,0.f,0.f,0.f};
            acc2 = {0.f,0.f,0.f,0.f}; acc3 = {0.f,0.f,0.f,0.f};
            GEMM_EVEN(sb0, 0)
        } else {
            GEMM_EVEN(sb1, 4)
            const int c0 = Cb + ct * 64 + l15;
            APPEND_SITE(acc0, 0)
            APPEND_SITE(acc1, 16)
            APPEND_SITE(acc2, 32)
            APPEND_SITE(acc3, 48)
        }
        if (more) {
            if (hN) STAGE_WRITE(sb1) else STAGE_WRITE(sb0)
        }
        __syncthreads();
    }

    if (threadIdx.x < 64)
        cntg[(size_t)(rb * 64 + threadIdx.x) * NCH + chunk] = lcnt[threadIdx.x];
#undef APPEND_SITE
}

// ---------- 5) k_sel: WAVE-PARALLEL per-row select + degrees ----------
// 16 lanes/row, strided bucket reads, butterfly merge (lane-unique sentinels);
// synthetic diag key by lane 0 only -> o_i == 8 for any bucket-drop pattern.
__global__ void k_sel(const unsigned* __restrict__ bufg, const unsigned* __restrict__ cntg,
                      unsigned capc, unsigned* __restrict__ dd, unsigned* __restrict__ gg) {
    const int w = threadIdx.x >> 6, lane = threadIdx.x & 63;
    const int l15 = lane & 15, lg = lane >> 4;
    const int row = blockIdx.x * 16 + w * 4 + lg;

    unsigned a[9]; unsigned mn = (unsigned)(l15 * 16);
#pragma unroll
    for (int k = 0; k < 9; ++k) a[k] = (unsigned)(l15 * 16 + k);   // lane-unique
    if (l15 == 0) top9u(a, mn, 0xFFFFC000u | (unsigned)row);       // synthetic diag
#pragma unroll
    for (int c = 0; c < NCH; ++c) {
        const unsigned n = min(cntg[(size_t)row * NCH + c], capc);
        const unsigned* b = bufg + ((size_t)row * NCH + c) * capc;
        for (unsigned t = l15; t < n; t += 16) {
            const unsigned key = b[t];
            if ((key & 16383u) != (unsigned)row) top9u(a, mn, key);
        }
    }
#pragma unroll
    for (int off = 1; off < 16; off <<= 1) {
        unsigned o[9];
#pragma unroll
        for (int k = 0; k < 9; ++k) o[k] = (unsigned)__shfl_xor((int)a[k], off);
#pragma unroll
        for (int k = 0; k < 9; ++k) top9u(a, mn, o[k]);
    }
    const unsigned thr = mn;   // exact 9th of {synth diag} u off-diag survivors
    unsigned o = 0;
#pragma unroll
    for (int c = 0; c < NCH; ++c) {
        const unsigned n = min(cntg[(size_t)row * NCH + c], capc);
        const unsigned* b = bufg + ((size_t)row * NCH + c) * capc;
        for (unsigned t = l15; t < n; t += 16) {
            const unsigned key = b[t];
            const int col = (int)(key & 16383u);
            if (key >= thr && col != row) { ++o; atomicAdd(&gg[col], 1u); }
        }
    }
#pragma unroll
    for (int off = 1; off < 16; off <<= 1) o += (unsigned)__shfl_xor((int)o, off);
    if (l15 == 0) dd[row] = o;
}

// ---------- 6) wsum = sum_i o*d + g*d - 2o, d = max(o,1) ----------
__global__ void k_wsum(const unsigned* __restrict__ dd, const unsigned* __restrict__ gg,
                       unsigned long long* __restrict__ wsum) {
    const int i = blockIdx.x * 256 + threadIdx.x;
    const unsigned long long o = dd[i];
    const unsigned long long g = gg[i];
    const unsigned long long d = o ? o : 1ull;
    unsigned long long acc = o * d + g * d - 2ull * o;
#pragma unroll
    for (int off = 32; off > 0; off >>= 1) acc += __shfl_xor(acc, off);
    if ((threadIdx.x & 63) == 0 && acc) atomicAdd(wsum, acc);
}

// ---------- 7) finalize ----------
__global__ void k_fin(const unsigned long long* __restrict__ wsum, float* __restrict__ out) {
    out[0] = (float)((double)*wsum * (0.01 / ((double)NR * (double)NR)));
}

extern "C" void kernel_launch(void* const* d_in, const int* in_sizes, int n_in,
                              void* d_out, int out_size, void* d_ws, size_t ws_size,
                              hipStream_t stream) {
    const float* x = (const float*)d_in[0];
    float* out = (float*)d_out;
    char* ws = (char*)d_ws;

    size_t off = 0;
    unsigned short* emb = (unsigned short*)(ws + off); off += (size_t)NR * DIMS * 2;        // 6.29 MB
    unsigned* s9p = (unsigned*)(ws + off);            off += (size_t)NR * NCH0 * TOPP * 4;  // 1.77 MB
    float* thrF = (float*)(ws + off);                 off += (size_t)NR * 4;
    unsigned* cntg = (unsigned*)(ws + off);           off += (size_t)NR * NCH * 4;          // 393 KB
    unsigned* dd = (unsigned*)(ws + off);             off += (size_t)NR * 4;
    unsigned* gg = (unsigned*)(ws + off);             off += (size_t)NR * 4;
    unsigned long long* wsum = (unsigned long long*)(ws + off); off += 64;
    unsigned* bufg = (unsigned*)(ws + off);
    // per-(row,chunk) bucket capacity; drops are output-invariant (see k_sel)
    size_t rem = (ws_size > off) ? (ws_size - off) / ((size_t)NR * NCH * 4) : 8;
    unsigned capc = (unsigned)(rem < 8 ? 8 : (rem > 32 ? 32 : rem));

    hipMemsetAsync(gg, 0, (size_t)NR * 4, stream);
    hipMemsetAsync(wsum, 0, 8, stream);

    k_norm<<<NR / 4, 256, 0, stream>>>(x, emb);
    k_sub9<<<(NR / 64) * NCH0, 256, 0, stream>>>(emb, s9p);
    k_thrm<<<NR / 256, 256, 0, stream>>>(s9p, thrF);
    k_main<<<(NR / 64) * NCH, 256, 0, stream>>>(emb, thrF, bufg, cntg, capc);
    k_sel<<<NR / 16, 256, 0, stream>>>(bufg, cntg, capc, dd, gg);
    k_wsum<<<NR / 256, 256, 0, stream>>>(dd, gg, wsum);
    k_fin<<<1, 1, 0, stream>>>(wsum, out);
}